// Round 2
// baseline (282.065 us; speedup 1.0000x reference)
//
#include <hip/hip_runtime.h>

// Problem dims (fixed)
#define BB   4
#define LQ   1024
#define LK   2048
#define D1   1024
#define D2   1280

typedef unsigned short u16;
typedef __attribute__((ext_vector_type(8))) short   short8;   // 8 bf16 = 4 VGPRs
typedef __attribute__((ext_vector_type(4))) float   floatx4;  // MFMA accum

__device__ __forceinline__ u16 f2bf(float f) {
    unsigned u = __float_as_uint(f);
    unsigned r = (u + 0x7FFFu + ((u >> 16) & 1u)) >> 16;   // RNE
    return (u16)r;
}

// async global->LDS, 16B per lane; LDS dest = wave-uniform base + lane*16
__device__ __forceinline__ void gl_lds16(const void* g, void* l) {
    __builtin_amdgcn_global_load_lds(
        (const __attribute__((address_space(1))) unsigned int*)g,
        (__attribute__((address_space(3))) unsigned int*)l, 16, 0, 0);
}

// ---------------------------------------------------------------------------
// Batched fp32 -> bf16 cast (R7-measured-fastest form). Also zeroes rsum.
// ---------------------------------------------------------------------------
struct CastDesc {
    const float* src[6];
    u16*         dst[6];
    long         end[6];      // cumulative end in QUADS (4 elems)
};

__global__ __launch_bounds__(256) void cast6_kernel(CastDesc d, long total_quads,
                                                    float* __restrict__ rs0)
{
    if (blockIdx.x < 16)
        rs0[blockIdx.x * 256 + threadIdx.x] = 0.f;   // 16*256 = 4096 = BB*LQ

    long gi = (long)blockIdx.x * 256 + threadIdx.x;
    if (gi >= total_quads) return;
    int s = 0;
    while (gi >= d.end[s]) ++s;            // 6 segments, short loop
    const long start = (s == 0) ? 0 : d.end[s - 1];
    const long q = gi - start;
    const float4 v = *(const float4*)(d.src[s] + q * 4);
    ushort4 o;
    o.x = f2bf(v.x); o.y = f2bf(v.y); o.z = f2bf(v.z); o.w = f2bf(v.w);
    *(ushort4*)(d.dst[s] + q * 4) = o;
}

enum { EPI_F32_BIAS, EPI_KV, EPI_EXP, EPI_ROWSCALE };

// ---------------------------------------------------------------------------
// mm_bf16: R12 kernel (m97-style 2-barrier). Used for ctx (EPI_ROWSCALE)
// and out-proj (EPI_F32_BIAS) whose 256^2 grids would be too small
// (64 blocks) for the 8-phase kernel.
// ---------------------------------------------------------------------------
template <int BM, int BN, int EPI>
__global__ __launch_bounds__(256, 2) void mm_bf16(
    const u16* __restrict__ A, const u16* __restrict__ B,
    void* __restrict__ C, const float* __restrict__ bias,
    int nx, int Kd, int lda, int ldb, int ldc,
    long sA, long sB, long sC, float scale,
    const u16* __restrict__ A2, const u16* __restrict__ B2,
    void* __restrict__ C2, const float* __restrict__ bias2,
    int ldc2, long sC2, float* __restrict__ rsum)
{
    constexpr bool TALL = (BM == 256);
    constexpr int  NJ   = TALL ? (BN / 16) : (BN / 32);  // j-frags per wave
    constexpr int  AISS = BM / 32;    // A staging issues per thread
    constexpr int  NBI  = BN / 32;    // B staging issues per thread

    __shared__ u16 As[BM * 64];      // [m][k] swizzled
    __shared__ u16 Bs[BN * 64];      // [n][k] swizzled

    const int u    = blockIdx.x;
    const int rest = u >> 3;
    const int bx   = rest % nx;
    const int by   = (u & 7) + 8 * (rest / nx);

    const int  bz  = blockIdx.z;
    const bool isV = (EPI == EPI_KV) && (bz >= BB);
    const int  b   = isV ? bz - BB : bz;

    const u16* Ab = (isV ? A2 : A) + (long)b * sA + (long)by * BM * lda;
    const u16* Bb = (isV ? B2 : B) + (long)b * sB + (long)bx * BN * ldb;

    const int t    = threadIdx.x;
    const int w    = t >> 6;              // wave 0..3
    const int l    = t & 63;
    const int l16  = l & 15;
    const int quad = l >> 4;
    const int wm   = TALL ? w * 64 : (w >> 1) * 64;
    const int wn   = TALL ? 0      : (w & 1) * (BN / 2);

    floatx4 acc[4][NJ];
    #pragma unroll
    for (int i = 0; i < 4; ++i)
        #pragma unroll
        for (int j = 0; j < NJ; ++j)
            acc[i][j] = (floatx4){0.f, 0.f, 0.f, 0.f};

    for (int k0 = 0; k0 < Kd; k0 += 64) {
        #pragma unroll
        for (int c = 0; c < AISS; ++c) {
            const int idx = (w * AISS + c) * 64 + l;
            const int mr  = idx >> 3;
            const int kq  = (idx & 7) ^ (mr & 7);
            gl_lds16(Ab + (long)mr * lda + k0 + kq * 8, (char*)As + (w * AISS + c) * 1024);
        }
        #pragma unroll
        for (int c = 0; c < NBI; ++c) {
            const int idx = (w * NBI + c) * 64 + l;
            const int mr  = idx >> 3;
            const int kq  = (idx & 7) ^ (mr & 7);
            gl_lds16(Bb + (long)mr * ldb + k0 + kq * 8, (char*)Bs + (w * NBI + c) * 1024);
        }
        __syncthreads();

        #pragma unroll
        for (int q = 0; q < 2; ++q) {
            const int sc = ((q * 4 + quad) ^ (l & 7)) * 8;
            short8 af[4], bfr[NJ];
            #pragma unroll
            for (int i = 0; i < 4; ++i)
                af[i]  = *(const short8*)(As + (wm + i * 16 + l16) * 64 + sc);
            #pragma unroll
            for (int j = 0; j < NJ; ++j)
                bfr[j] = *(const short8*)(Bs + (wn + j * 16 + l16) * 64 + sc);
            #pragma unroll
            for (int i = 0; i < 4; ++i)
                #pragma unroll
                for (int j = 0; j < NJ; ++j)
                    acc[i][j] = __builtin_amdgcn_mfma_f32_16x16x32_bf16(
                        af[i], bfr[j], acc[i][j], 0, 0, 0);
        }
        __syncthreads();
    }

    const int mb = by * BM + wm;
    const int nb = bx * BN + wn;

    if (EPI == EPI_F32_BIAS) {
        float* Cp = (float*)C + (long)bz * sC;
        #pragma unroll
        for (int i = 0; i < 4; ++i)
            #pragma unroll
            for (int j = 0; j < NJ; ++j) {
                const int col  = nb + j * 16 + l16;
                const int row0 = mb + i * 16 + quad * 4;
                const float bs = bias[col];
                #pragma unroll
                for (int r = 0; r < 4; ++r)
                    Cp[(long)(row0 + r) * ldc + col] = acc[i][j][r] + bs;
            }
    } else if (EPI == EPI_KV) {
        if (!isV) {
            u16* Cp = (u16*)C + (long)b * sC;
            #pragma unroll
            for (int i = 0; i < 4; ++i)
                #pragma unroll
                for (int j = 0; j < NJ; ++j) {
                    const int col  = nb + j * 16 + l16;
                    const int row0 = mb + i * 16 + quad * 4;
                    const float bs = bias[col];
                    #pragma unroll
                    for (int r = 0; r < 4; ++r)
                        Cp[(long)(row0 + r) * ldc + col] = f2bf(acc[i][j][r] + bs);
                }
        } else {
            u16* Cp = (u16*)C2 + (long)b * sC2;
            #pragma unroll
            for (int i = 0; i < 4; ++i)
                #pragma unroll
                for (int j = 0; j < NJ; ++j) {
                    const int col  = nb + j * 16 + l16;
                    const int row0 = mb + i * 16 + quad * 4;
                    const float bs = bias2[col];
                    const floatx4 vv = acc[i][j];
                    ushort4 pk;
                    pk.x = f2bf(vv[0] + bs); pk.y = f2bf(vv[1] + bs);
                    pk.z = f2bf(vv[2] + bs); pk.w = f2bf(vv[3] + bs);
                    *(ushort4*)(Cp + (long)col * ldc2 + row0) = pk;
                }
        }
    } else if (EPI == EPI_EXP) {
        u16* Cp = (u16*)C + (long)bz * sC;
        float lsum[4][4];
        #pragma unroll
        for (int i = 0; i < 4; ++i)
            #pragma unroll
            for (int r = 0; r < 4; ++r)
                lsum[i][r] = 0.f;
        #pragma unroll
        for (int i = 0; i < 4; ++i)
            #pragma unroll
            for (int j = 0; j < NJ; ++j) {
                const int col  = nb + j * 16 + l16;
                const int row0 = mb + i * 16 + quad * 4;
                #pragma unroll
                for (int r = 0; r < 4; ++r) {
                    const float e = __expf(acc[i][j][r] * scale);
                    Cp[(long)(row0 + r) * ldc + col] = f2bf(e);
                    lsum[i][r] += e;
                }
            }
        float* rp = rsum + (long)bz * LQ;
        #pragma unroll
        for (int i = 0; i < 4; ++i)
            #pragma unroll
            for (int r = 0; r < 4; ++r) {
                float s = lsum[i][r];
                s += __shfl_xor(s, 1);
                s += __shfl_xor(s, 2);
                s += __shfl_xor(s, 4);
                s += __shfl_xor(s, 8);
                if (l16 == 0)
                    atomicAdd(rp + mb + i * 16 + quad * 4 + r, s);
            }
    } else { // EPI_ROWSCALE
        u16* Cp = (u16*)C + (long)bz * sC;
        const float* rp = rsum + (long)bz * LQ;
        #pragma unroll
        for (int i = 0; i < 4; ++i) {
            const int row0 = mb + i * 16 + quad * 4;
            float inv[4];
            #pragma unroll
            for (int r = 0; r < 4; ++r)
                inv[r] = 1.0f / rp[row0 + r];
            #pragma unroll
            for (int j = 0; j < NJ; ++j) {
                const int col = nb + j * 16 + l16;
                #pragma unroll
                for (int r = 0; r < 4; ++r)
                    Cp[(long)(row0 + r) * ldc + col] = f2bf(acc[i][j][r] * inv[r]);
            }
        }
    }
}

// ---------------------------------------------------------------------------
// mm256: 8-phase 256x256xBK64 schedule (T2+T3+T4+T5), plain HIP.
// 512 threads = 8 waves (2M x 4N), per-wave 128x64 output (acc[8][4]).
// LDS 128 KiB: [tensor A/B][dbuf slot 0/1][256 rows][64 k] bf16, XOR-swizzled
// at 16B-chunk granularity (chunk ^= row&7) -> conflict-free ds_read_b128.
// One half-tile (128 rows x 64 k = 2 x gl_lds16/thread) staged per phase;
// counted s_waitcnt vmcnt(4) only at phases 4 & 8 (never 0 mid-loop);
// setprio(1) around each 16-MFMA cluster; raw s_barrier (no drain).
//
// Stage schedule (iter j computes T0=2j from slot0 at P1-4, T1=2j+1 from
// slot1 at P5-8). Victim's last READ phase is strictly before the stage's
// ISSUE phase, separated by a barrier => race-free:
//   P1: A-h0(T1)   victim A-h0(2j-1) last read prev-P7
//   P2: A-h1(T1)   victim last read prev-P7
//   P3: B-h0(T0+2) victim B-h0(T0) last read P2   (b0 kept in regs, no P4 re-read)
//   P4: B-h1(T0+2) victim last read P2            + vmcnt(4): T1 landed
//   P5: A-h0(T0+2) victim A(T0) last read P3
//   P6: A-h1(T0+2) victim last read P3
//   P7: B-h0(T1+2) victim B(T1) last read P6
//   P8: B-h1(T1+2) victim last read P6            + vmcnt(4): T0+2 landed
// vmcnt bookkeeping (per wave, 2 vmem instrs per STG): prologue drains to 0
// via __syncthreads; at P4 outstanding = prevP7,P8,P1..P4 = 12, vmcnt(4)
// completes the oldest 8 = all of T1; at P8 outstanding = P3..P8 = 12,
// vmcnt(4) completes P3..P6 = all of T0+2. K-tail: stages guarded
// (tile >= NT skipped); last iter waits vmcnt(0).
// ---------------------------------------------------------------------------
template <int EPI>
__global__ __launch_bounds__(512, 2) void mm256(
    const u16* __restrict__ A, const u16* __restrict__ B,
    void* __restrict__ C, const float* __restrict__ bias,
    int nx, int Kd, int lda, int ldb, int ldc,
    long sA, long sB, long sC, float scale,
    const u16* __restrict__ A2, const u16* __restrict__ B2,
    void* __restrict__ C2, const float* __restrict__ bias2,
    int ldc2, long sC2, float* __restrict__ rsum)
{
    const int NT = Kd >> 6;                 // K-tiles (even for all our uses)
    __shared__ u16 sh[2][2][256][64];       // 128 KiB

    // XCD-aware bijective decode (grid.x % 8 == 0 for all uses)
    const int u     = blockIdx.x;
    const int chunk = (int)gridDim.x >> 3;
    const int v     = (u & 7) * chunk + (u >> 3);
    const int bx = v % nx, by = v / nx;

    const int  bz  = blockIdx.z;
    const bool isV = (EPI == EPI_KV) && (bz >= BB);
    const int  b   = isV ? bz - BB : bz;
    const u16* Ab = (isV ? A2 : A) + (long)b * sA + (long)by * 256 * lda;
    const u16* Bb = (isV ? B2 : B) + (long)b * sB + (long)bx * 256 * ldb;

    const int t    = threadIdx.x;
    const int w    = t >> 6;          // wave 0..7
    const int l    = t & 63;
    const int l16  = l & 15;
    const int quad = l >> 4;
    const int wm   = (w >> 2) * 128;  // wave M origin
    const int wn   = (w & 3) * 64;    // wave N origin

    floatx4 acc[8][4];
    #pragma unroll
    for (int i = 0; i < 8; ++i)
        #pragma unroll
        for (int jn = 0; jn < 4; ++jn)
            acc[i][jn] = (floatx4){0.f, 0.f, 0.f, 0.f};

    // stage one half-tile: sub 0=A-h0 1=A-h1 2=B-h0 3=B-h1
    auto STG = [&](int tile, int sub) {
        if (tile >= NT) return;
        const int slot = tile & 1, tensor = sub >> 1, half = sub & 1;
        const u16* src = tensor ? Bb : Ab;
        const int  ld  = tensor ? ldb : lda;
        const int  k0  = tile << 6;
        char* dst = (char*)(&sh[tensor][slot][half * 128][0]) + w * 1024;
        #pragma unroll
        for (int c = 0; c < 2; ++c) {
            const int idx = c * 512 + t;
            const int r   = idx >> 3;
            const int kq  = (idx & 7) ^ (r & 7);         // pre-swizzled source
            gl_lds16(src + (long)(half * 128 + r) * ld + k0 + kq * 8, dst + c * 8192);
        }
    };
    auto RDA = [&](short8 (&a)[4][2], int slot, int mi0) {
        #pragma unroll
        for (int i = 0; i < 4; ++i)
            #pragma unroll
            for (int q = 0; q < 2; ++q)
                a[i][q] = *(const short8*)&sh[0][slot][wm + (mi0 + i) * 16 + l16]
                                            [((q * 4 + quad) ^ (l16 & 7)) * 8];
    };
    auto RDB = [&](short8 (&bf)[2][2], int slot, int nj0) {
        #pragma unroll
        for (int n = 0; n < 2; ++n)
            #pragma unroll
            for (int q = 0; q < 2; ++q)
                bf[n][q] = *(const short8*)&sh[1][slot][wn + (nj0 + n) * 16 + l16]
                                             [((q * 4 + quad) ^ (l16 & 7)) * 8];
    };
    auto MM16 = [&](short8 (&a)[4][2], short8 (&bf)[2][2], int m0, int n0) {
        __builtin_amdgcn_s_setprio(1);
        #pragma unroll
        for (int q = 0; q < 2; ++q)
            #pragma unroll
            for (int i = 0; i < 4; ++i)
                #pragma unroll
                for (int n = 0; n < 2; ++n)
                    acc[m0 + i][n0 + n] = __builtin_amdgcn_mfma_f32_16x16x32_bf16(
                        a[i][q], bf[n][q], acc[m0 + i][n0 + n], 0, 0, 0);
        __builtin_amdgcn_s_setprio(0);
    };

    // ---- prologue: tile0 complete + B(1) issued; __syncthreads drains all
    STG(0, 0); STG(0, 1); STG(0, 2); STG(0, 3);
    STG(1, 2); STG(1, 3);
    __syncthreads();

    short8 am[4][2], b0[2][2], b1[2][2];
    const int iters = NT >> 1;
    for (int j = 0; j < iters; ++j) {
        const int  T1   = 2 * j + 1;
        const bool deep = (j + 1 < iters);
        // P1
        RDA(am, 0, 0); RDB(b0, 0, 0);
        STG(T1, 0);
        __builtin_amdgcn_s_barrier();
        MM16(am, b0, 0, 0);
        __builtin_amdgcn_s_barrier();
        // P2
        RDB(b1, 0, 2);
        STG(T1, 1);
        __builtin_amdgcn_s_barrier();
        MM16(am, b1, 0, 2);
        __builtin_amdgcn_s_barrier();
        // P3
        RDA(am, 0, 4);
        STG(T1 + 1, 2);
        __builtin_amdgcn_s_barrier();
        MM16(am, b1, 4, 2);
        __builtin_amdgcn_s_barrier();
        // P4
        STG(T1 + 1, 3);
        if (deep) asm volatile("s_waitcnt vmcnt(4)" ::: "memory");
        else      asm volatile("s_waitcnt vmcnt(0)" ::: "memory");
        __builtin_amdgcn_s_barrier();
        MM16(am, b0, 4, 0);
        __builtin_amdgcn_s_barrier();
        // P5
        RDA(am, 1, 0); RDB(b0, 1, 0);
        STG(T1 + 1, 0);
        __builtin_amdgcn_s_barrier();
        MM16(am, b0, 0, 0);
        __builtin_amdgcn_s_barrier();
        // P6
        RDB(b1, 1, 2);
        STG(T1 + 1, 1);
        __builtin_amdgcn_s_barrier();
        MM16(am, b1, 0, 2);
        __builtin_amdgcn_s_barrier();
        // P7
        RDA(am, 1, 4);
        STG(T1 + 2, 2);
        __builtin_amdgcn_s_barrier();
        MM16(am, b1, 4, 2);
        __builtin_amdgcn_s_barrier();
        // P8
        STG(T1 + 2, 3);
        if (deep) asm volatile("s_waitcnt vmcnt(4)" ::: "memory");
        else      asm volatile("s_waitcnt vmcnt(0)" ::: "memory");
        __builtin_amdgcn_s_barrier();
        MM16(am, b0, 4, 0);
        __builtin_amdgcn_s_barrier();
    }

    // ---- epilogue: C/D layout col = lane&15, row = quad*4 + reg
    const int mb = by * 256 + wm;
    const int nb = bx * 256 + wn;

    if (EPI == EPI_KV) {
        if (!isV) {        // K-proj: row-major bf16 + bias
            u16* Cp = (u16*)C + (long)b * sC;
            #pragma unroll
            for (int i = 0; i < 8; ++i)
                #pragma unroll
                for (int jn = 0; jn < 4; ++jn) {
                    const int col  = nb + jn * 16 + l16;
                    const int row0 = mb + i * 16 + quad * 4;
                    const float bs = bias[col];
                    #pragma unroll
                    for (int r = 0; r < 4; ++r)
                        Cp[(long)(row0 + r) * ldc + col] = f2bf(acc[i][jn][r] + bs);
                }
        } else {           // V-proj: transposed store C2^T[col][row0..+3]
            u16* Cp = (u16*)C2 + (long)b * sC2;
            #pragma unroll
            for (int i = 0; i < 8; ++i)
                #pragma unroll
                for (int jn = 0; jn < 4; ++jn) {
                    const int col  = nb + jn * 16 + l16;
                    const int row0 = mb + i * 16 + quad * 4;
                    const float bs = bias2[col];
                    const floatx4 vv = acc[i][jn];
                    ushort4 pk;
                    pk.x = f2bf(vv[0] + bs); pk.y = f2bf(vv[1] + bs);
                    pk.z = f2bf(vv[2] + bs); pk.w = f2bf(vv[3] + bs);
                    *(ushort4*)(Cp + (long)col * ldc2 + row0) = pk;
                }
        }
    } else if (EPI == EPI_EXP) {
        u16* Cp = (u16*)C + (long)bz * sC;
        float lsum[8][4];
        #pragma unroll
        for (int i = 0; i < 8; ++i)
            #pragma unroll
            for (int r = 0; r < 4; ++r)
                lsum[i][r] = 0.f;
        #pragma unroll
        for (int i = 0; i < 8; ++i)
            #pragma unroll
            for (int jn = 0; jn < 4; ++jn) {
                const int col  = nb + jn * 16 + l16;
                const int row0 = mb + i * 16 + quad * 4;
                #pragma unroll
                for (int r = 0; r < 4; ++r) {
                    const float e = __expf(acc[i][jn][r] * scale);
                    Cp[(long)(row0 + r) * ldc + col] = f2bf(e);
                    lsum[i][r] += e;
                }
            }
        float* rp = rsum + (long)bz * LQ;
        #pragma unroll
        for (int i = 0; i < 8; ++i)
            #pragma unroll
            for (int r = 0; r < 4; ++r) {
                float s = lsum[i][r];
                s += __shfl_xor(s, 1);
                s += __shfl_xor(s, 2);
                s += __shfl_xor(s, 4);
                s += __shfl_xor(s, 8);
                if (l16 == 0)
                    atomicAdd(rp + mb + i * 16 + quad * 4 + r, s);
            }
    }
}

// ---------------------------------------------------------------------------
extern "C" void kernel_launch(void* const* d_in, const int* in_sizes, int n_in,
                              void* d_out, int out_size, void* d_ws, size_t ws_size,
                              hipStream_t stream)
{
    const float* Q  = (const float*)d_in[0];
    const float* K  = (const float*)d_in[1];
    const float* V  = (const float*)d_in[2];
    const float* Wk = (const float*)d_in[3];
    const float* bk = (const float*)d_in[4];
    const float* Wv = (const float*)d_in[5];
    const float* bv = (const float*)d_in[6];
    const float* Wo = (const float*)d_in[7];
    const float* bo = (const float*)d_in[8];
    float* out = (float*)d_out;

    // Workspace layout (max extent 94.4 MB + 16 KB):
    char* ws = (char*)d_ws;
    u16*   Kbf  = (u16*)(ws);
    u16*   Vbf  = (u16*)(ws + 22020096);
    u16*   Qbf  = (u16*)(ws + 44040192);
    u16*   Wkbf = (u16*)(ws + 52828160);
    u16*   Wvbf = (u16*)(ws + 55574528);
    u16*   Wobf = (u16*)(ws + 58320896);
    u16*   Kp   = (u16*)(ws + 60817408);
    u16*   VpT  = (u16*)(ws + 77594624);
    u16*   E    = (u16*)(ws);
    float* rsum = (float*)(ws + 94371840);
    u16*   Ctx  = Kp;

    const float inv_sqrt_d = 0.03125f;   // 1/sqrt(1024)

    // ---- one batched cast launch (also zeroes rsum)
    CastDesc cd;
    cd.src[0] = K;  cd.dst[0] = Kbf;
    cd.src[1] = V;  cd.dst[1] = Vbf;
    cd.src[2] = Q;  cd.dst[2] = Qbf;
    cd.src[3] = Wk; cd.dst[3] = Wkbf;
    cd.src[4] = Wv; cd.dst[4] = Wvbf;
    cd.src[5] = Wo; cd.dst[5] = Wobf;
    long acc = 0;
    const long sizes[6] = {(long)BB*LK*D2, (long)BB*LK*D2, (long)BB*LQ*D1,
                           (long)D1*D2, (long)D1*D2, (long)D1*D1};
    for (int i = 0; i < 6; ++i) { acc += sizes[i] / 4; cd.end[i] = acc; }
    cast6_kernel<<<dim3((unsigned)((acc + 255) / 256)), 256, 0, stream>>>(cd, acc, rsum);

    // ---- merged K/V projections: 8-phase 256x256, grid 32 x z=8 = 256 blocks
    mm256<EPI_KV><<<dim3((D1/256)*(LK/256), 1, 2*BB), 512, 0, stream>>>(
        Kbf, Wkbf, Kp, bk, D1/256, D2, D2, D2, D1,
        (long)LK*D2, 0, (long)LK*D1, 1.0f,
        Vbf, Wvbf, VpT, bv, LK, (long)D1*LK, nullptr);

    // ---- fused scores+exp: 8-phase 256x256, grid 32 x z=4 = 128 blocks
    mm256<EPI_EXP><<<dim3((LK/256)*(LQ/256), 1, BB), 512, 0, stream>>>(
        Qbf, Kp, E, nullptr, LK/256, D1, D1, D1, LK,
        (long)LQ*D1, (long)LK*D1, (long)LQ*LK, inv_sqrt_d,
        nullptr, nullptr, nullptr, nullptr, 0, 0, rsum);

    // ---- context with fused normalization: Ctx = (E @ VpT^T) / rsum[row]
    mm_bf16<128, 64, EPI_ROWSCALE><<<dim3((D1/64)*(LQ/128), 1, BB), 256, 0, stream>>>(
        E, VpT, Ctx, nullptr, D1/64, LK, LK, LK, D1,
        (long)LQ*LK, (long)D1*LK, (long)LQ*D1, 1.0f,
        nullptr, nullptr, nullptr, nullptr, 0, 0, rsum);

    // ---- output: out = Ctx @ Wo^T + bo
    mm_bf16<128, 64, EPI_F32_BIAS><<<dim3((D1/64)*((BB*LQ)/128), 1, 1), 256, 0, stream>>>(
        Ctx, Wobf, out, bo, D1/64, D1, D1, D1, D1, 0, 0, 0, 1.0f,
        nullptr, nullptr, nullptr, nullptr, 0, 0, nullptr);
}

// Round 3
// 272.408 us; speedup vs baseline: 1.0354x; 1.0354x over previous
//
#include <hip/hip_runtime.h>

// Problem dims (fixed)
#define BB   4
#define LQ   1024
#define LK   2048
#define D1   1024
#define D2   1280

typedef unsigned short u16;
typedef __attribute__((ext_vector_type(8))) short   short8;   // 8 bf16 = 4 VGPRs
typedef __attribute__((ext_vector_type(4))) float   floatx4;  // MFMA accum

__device__ __forceinline__ u16 f2bf(float f) {
    unsigned u = __float_as_uint(f);
    unsigned r = (u + 0x7FFFu + ((u >> 16) & 1u)) >> 16;   // RNE
    return (u16)r;
}

// async global->LDS, 16B per lane; LDS dest = wave-uniform base + lane*16
__device__ __forceinline__ void gl_lds16(const void* g, void* l) {
    __builtin_amdgcn_global_load_lds(
        (const __attribute__((address_space(1))) unsigned int*)g,
        (__attribute__((address_space(3))) unsigned int*)l, 16, 0, 0);
}

// ---------------------------------------------------------------------------
// Batched fp32 -> bf16 cast (R7-measured-fastest form). Also zeroes rsum.
// ---------------------------------------------------------------------------
struct CastDesc {
    const float* src[6];
    u16*         dst[6];
    long         end[6];      // cumulative end in QUADS (4 elems)
};

__global__ __launch_bounds__(256) void cast6_kernel(CastDesc d, long total_quads,
                                                    float* __restrict__ rs0)
{
    if (blockIdx.x < 16)
        rs0[blockIdx.x * 256 + threadIdx.x] = 0.f;   // 16*256 = 4096 = BB*LQ

    long gi = (long)blockIdx.x * 256 + threadIdx.x;
    if (gi >= total_quads) return;
    int s = 0;
    while (gi >= d.end[s]) ++s;            // 6 segments, short loop
    const long start = (s == 0) ? 0 : d.end[s - 1];
    const long q = gi - start;
    const float4 v = *(const float4*)(d.src[s] + q * 4);
    ushort4 o;
    o.x = f2bf(v.x); o.y = f2bf(v.y); o.z = f2bf(v.z); o.w = f2bf(v.w);
    *(ushort4*)(d.dst[s] + q * 4) = o;
}

enum { EPI_F32_BIAS, EPI_KV, EPI_EXP, EPI_ROWSCALE };

// ---------------------------------------------------------------------------
// mm_bf16: R12 kernel (m97-style 2-barrier). Used for scores (EPI_EXP, 512
// blocks — R13's mm256 grid of 128 blocks left half the GPU idle), ctx
// (EPI_ROWSCALE) and out-proj (EPI_F32_BIAS).
// ---------------------------------------------------------------------------
template <int BM, int BN, int EPI>
__global__ __launch_bounds__(256, 2) void mm_bf16(
    const u16* __restrict__ A, const u16* __restrict__ B,
    void* __restrict__ C, const float* __restrict__ bias,
    int nx, int Kd, int lda, int ldb, int ldc,
    long sA, long sB, long sC, float scale,
    const u16* __restrict__ A2, const u16* __restrict__ B2,
    void* __restrict__ C2, const float* __restrict__ bias2,
    int ldc2, long sC2, float* __restrict__ rsum)
{
    constexpr bool TALL = (BM == 256);
    constexpr int  NJ   = TALL ? (BN / 16) : (BN / 32);  // j-frags per wave
    constexpr int  AISS = BM / 32;    // A staging issues per thread
    constexpr int  NBI  = BN / 32;    // B staging issues per thread

    __shared__ u16 As[BM * 64];      // [m][k] swizzled
    __shared__ u16 Bs[BN * 64];      // [n][k] swizzled

    const int u    = blockIdx.x;
    const int rest = u >> 3;
    const int bx   = rest % nx;
    const int by   = (u & 7) + 8 * (rest / nx);

    const int  bz  = blockIdx.z;
    const bool isV = (EPI == EPI_KV) && (bz >= BB);
    const int  b   = isV ? bz - BB : bz;

    const u16* Ab = (isV ? A2 : A) + (long)b * sA + (long)by * BM * lda;
    const u16* Bb = (isV ? B2 : B) + (long)b * sB + (long)bx * BN * ldb;

    const int t    = threadIdx.x;
    const int w    = t >> 6;              // wave 0..3
    const int l    = t & 63;
    const int l16  = l & 15;
    const int quad = l >> 4;
    const int wm   = TALL ? w * 64 : (w >> 1) * 64;
    const int wn   = TALL ? 0      : (w & 1) * (BN / 2);

    floatx4 acc[4][NJ];
    #pragma unroll
    for (int i = 0; i < 4; ++i)
        #pragma unroll
        for (int j = 0; j < NJ; ++j)
            acc[i][j] = (floatx4){0.f, 0.f, 0.f, 0.f};

    for (int k0 = 0; k0 < Kd; k0 += 64) {
        #pragma unroll
        for (int c = 0; c < AISS; ++c) {
            const int idx = (w * AISS + c) * 64 + l;
            const int mr  = idx >> 3;
            const int kq  = (idx & 7) ^ (mr & 7);
            gl_lds16(Ab + (long)mr * lda + k0 + kq * 8, (char*)As + (w * AISS + c) * 1024);
        }
        #pragma unroll
        for (int c = 0; c < NBI; ++c) {
            const int idx = (w * NBI + c) * 64 + l;
            const int mr  = idx >> 3;
            const int kq  = (idx & 7) ^ (mr & 7);
            gl_lds16(Bb + (long)mr * ldb + k0 + kq * 8, (char*)Bs + (w * NBI + c) * 1024);
        }
        __syncthreads();

        #pragma unroll
        for (int q = 0; q < 2; ++q) {
            const int sc = ((q * 4 + quad) ^ (l & 7)) * 8;
            short8 af[4], bfr[NJ];
            #pragma unroll
            for (int i = 0; i < 4; ++i)
                af[i]  = *(const short8*)(As + (wm + i * 16 + l16) * 64 + sc);
            #pragma unroll
            for (int j = 0; j < NJ; ++j)
                bfr[j] = *(const short8*)(Bs + (wn + j * 16 + l16) * 64 + sc);
            #pragma unroll
            for (int i = 0; i < 4; ++i)
                #pragma unroll
                for (int j = 0; j < NJ; ++j)
                    acc[i][j] = __builtin_amdgcn_mfma_f32_16x16x32_bf16(
                        af[i], bfr[j], acc[i][j], 0, 0, 0);
        }
        __syncthreads();
    }

    const int mb = by * BM + wm;
    const int nb = bx * BN + wn;

    if (EPI == EPI_F32_BIAS) {
        float* Cp = (float*)C + (long)bz * sC;
        #pragma unroll
        for (int i = 0; i < 4; ++i)
            #pragma unroll
            for (int j = 0; j < NJ; ++j) {
                const int col  = nb + j * 16 + l16;
                const int row0 = mb + i * 16 + quad * 4;
                const float bs = bias[col];
                #pragma unroll
                for (int r = 0; r < 4; ++r)
                    Cp[(long)(row0 + r) * ldc + col] = acc[i][j][r] + bs;
            }
    } else if (EPI == EPI_KV) {
        if (!isV) {
            u16* Cp = (u16*)C + (long)b * sC;
            #pragma unroll
            for (int i = 0; i < 4; ++i)
                #pragma unroll
                for (int j = 0; j < NJ; ++j) {
                    const int col  = nb + j * 16 + l16;
                    const int row0 = mb + i * 16 + quad * 4;
                    const float bs = bias[col];
                    #pragma unroll
                    for (int r = 0; r < 4; ++r)
                        Cp[(long)(row0 + r) * ldc + col] = f2bf(acc[i][j][r] + bs);
                }
        } else {
            u16* Cp = (u16*)C2 + (long)b * sC2;
            #pragma unroll
            for (int i = 0; i < 4; ++i)
                #pragma unroll
                for (int j = 0; j < NJ; ++j) {
                    const int col  = nb + j * 16 + l16;
                    const int row0 = mb + i * 16 + quad * 4;
                    const float bs = bias2[col];
                    const floatx4 vv = acc[i][j];
                    ushort4 pk;
                    pk.x = f2bf(vv[0] + bs); pk.y = f2bf(vv[1] + bs);
                    pk.z = f2bf(vv[2] + bs); pk.w = f2bf(vv[3] + bs);
                    *(ushort4*)(Cp + (long)col * ldc2 + row0) = pk;
                }
        }
    } else if (EPI == EPI_EXP) {
        u16* Cp = (u16*)C + (long)bz * sC;
        float lsum[4][4];
        #pragma unroll
        for (int i = 0; i < 4; ++i)
            #pragma unroll
            for (int r = 0; r < 4; ++r)
                lsum[i][r] = 0.f;
        #pragma unroll
        for (int i = 0; i < 4; ++i)
            #pragma unroll
            for (int j = 0; j < NJ; ++j) {
                const int col  = nb + j * 16 + l16;
                const int row0 = mb + i * 16 + quad * 4;
                #pragma unroll
                for (int r = 0; r < 4; ++r) {
                    const float e = __expf(acc[i][j][r] * scale);
                    Cp[(long)(row0 + r) * ldc + col] = f2bf(e);
                    lsum[i][r] += e;
                }
            }
        float* rp = rsum + (long)bz * LQ;
        #pragma unroll
        for (int i = 0; i < 4; ++i)
            #pragma unroll
            for (int r = 0; r < 4; ++r) {
                float s = lsum[i][r];
                s += __shfl_xor(s, 1);
                s += __shfl_xor(s, 2);
                s += __shfl_xor(s, 4);
                s += __shfl_xor(s, 8);
                if (l16 == 0)
                    atomicAdd(rp + mb + i * 16 + quad * 4 + r, s);
            }
    } else { // EPI_ROWSCALE
        u16* Cp = (u16*)C + (long)bz * sC;
        const float* rp = rsum + (long)bz * LQ;
        #pragma unroll
        for (int i = 0; i < 4; ++i) {
            const int row0 = mb + i * 16 + quad * 4;
            float inv[4];
            #pragma unroll
            for (int r = 0; r < 4; ++r)
                inv[r] = 1.0f / rp[row0 + r];
            #pragma unroll
            for (int j = 0; j < NJ; ++j) {
                const int col = nb + j * 16 + l16;
                #pragma unroll
                for (int r = 0; r < 4; ++r)
                    Cp[(long)(row0 + r) * ldc + col] = f2bf(acc[i][j][r] * inv[r]);
            }
        }
    }
}

// ---------------------------------------------------------------------------
// mm256: 8-phase 256x256xBK64 schedule. R14 change: m201-faithful phase
// fencing. Bare s_barrier is IntrNoMem — the scheduler may move ds_reads /
// MFMAs across it, dissolving the phase discipline (R13 measured 31%
// MfmaUtil, identical to 2-phase). Now each pre-MFMA barrier is followed by
//   asm volatile("s_waitcnt lgkmcnt(0)" ::: "memory");   // compiler mem fence
//   __builtin_amdgcn_sched_barrier(0);                    // pin MFMA below
// exactly as in the m201 template (+rule 18). vmcnt(4) at P4/P8 unchanged.
// ---------------------------------------------------------------------------
template <int EPI>
__global__ __launch_bounds__(512, 2) void mm256(
    const u16* __restrict__ A, const u16* __restrict__ B,
    void* __restrict__ C, const float* __restrict__ bias,
    int nx, int Kd, int lda, int ldb, int ldc,
    long sA, long sB, long sC, float scale,
    const u16* __restrict__ A2, const u16* __restrict__ B2,
    void* __restrict__ C2, const float* __restrict__ bias2,
    int ldc2, long sC2, float* __restrict__ rsum)
{
    const int NT = Kd >> 6;                 // K-tiles (even for all our uses)
    __shared__ u16 sh[2][2][256][64];       // 128 KiB

    // XCD-aware bijective decode (grid.x % 8 == 0 for all uses)
    const int u     = blockIdx.x;
    const int chunk = (int)gridDim.x >> 3;
    const int v     = (u & 7) * chunk + (u >> 3);
    const int bx = v % nx, by = v / nx;

    const int  bz  = blockIdx.z;
    const bool isV = (EPI == EPI_KV) && (bz >= BB);
    const int  b   = isV ? bz - BB : bz;
    const u16* Ab = (isV ? A2 : A) + (long)b * sA + (long)by * 256 * lda;
    const u16* Bb = (isV ? B2 : B) + (long)b * sB + (long)bx * 256 * ldb;

    const int t    = threadIdx.x;
    const int w    = t >> 6;          // wave 0..7
    const int l    = t & 63;
    const int l16  = l & 15;
    const int quad = l >> 4;
    const int wm   = (w >> 2) * 128;  // wave M origin
    const int wn   = (w & 3) * 64;    // wave N origin

    floatx4 acc[8][4];
    #pragma unroll
    for (int i = 0; i < 8; ++i)
        #pragma unroll
        for (int jn = 0; jn < 4; ++jn)
            acc[i][jn] = (floatx4){0.f, 0.f, 0.f, 0.f};

    // stage one half-tile: sub 0=A-h0 1=A-h1 2=B-h0 3=B-h1
    auto STG = [&](int tile, int sub) {
        if (tile >= NT) return;
        const int slot = tile & 1, tensor = sub >> 1, half = sub & 1;
        const u16* src = tensor ? Bb : Ab;
        const int  ld  = tensor ? ldb : lda;
        const int  k0  = tile << 6;
        char* dst = (char*)(&sh[tensor][slot][half * 128][0]) + w * 1024;
        #pragma unroll
        for (int c = 0; c < 2; ++c) {
            const int idx = c * 512 + t;
            const int r   = idx >> 3;
            const int kq  = (idx & 7) ^ (r & 7);         // pre-swizzled source
            gl_lds16(src + (long)(half * 128 + r) * ld + k0 + kq * 8, dst + c * 8192);
        }
    };
    auto RDA = [&](short8 (&a)[4][2], int slot, int mi0) {
        #pragma unroll
        for (int i = 0; i < 4; ++i)
            #pragma unroll
            for (int q = 0; q < 2; ++q)
                a[i][q] = *(const short8*)&sh[0][slot][wm + (mi0 + i) * 16 + l16]
                                            [((q * 4 + quad) ^ (l16 & 7)) * 8];
    };
    auto RDB = [&](short8 (&bf)[2][2], int slot, int nj0) {
        #pragma unroll
        for (int n = 0; n < 2; ++n)
            #pragma unroll
            for (int q = 0; q < 2; ++q)
                bf[n][q] = *(const short8*)&sh[1][slot][wn + (nj0 + n) * 16 + l16]
                                             [((q * 4 + quad) ^ (l16 & 7)) * 8];
    };
    auto MM16 = [&](short8 (&a)[4][2], short8 (&bf)[2][2], int m0, int n0) {
        __builtin_amdgcn_s_setprio(1);
        #pragma unroll
        for (int q = 0; q < 2; ++q)
            #pragma unroll
            for (int i = 0; i < 4; ++i)
                #pragma unroll
                for (int n = 0; n < 2; ++n)
                    acc[m0 + i][n0 + n] = __builtin_amdgcn_mfma_f32_16x16x32_bf16(
                        a[i][q], bf[n][q], acc[m0 + i][n0 + n], 0, 0, 0);
        __builtin_amdgcn_s_setprio(0);
    };
    // pre-MFMA fence: barrier; wait all LDS reads of this phase; pin order.
    auto FENCE = [&]() {
        __builtin_amdgcn_s_barrier();
        asm volatile("s_waitcnt lgkmcnt(0)" ::: "memory");
        __builtin_amdgcn_sched_barrier(0);
    };

    // ---- prologue: tile0 complete + B(1) issued; __syncthreads drains all
    STG(0, 0); STG(0, 1); STG(0, 2); STG(0, 3);
    STG(1, 2); STG(1, 3);
    __syncthreads();

    short8 am[4][2], b0[2][2], b1[2][2];
    const int iters = NT >> 1;
    for (int j = 0; j < iters; ++j) {
        const int  T1   = 2 * j + 1;
        const bool deep = (j + 1 < iters);
        // P1
        RDA(am, 0, 0); RDB(b0, 0, 0);
        STG(T1, 0);
        FENCE();
        MM16(am, b0, 0, 0);
        __builtin_amdgcn_s_barrier();
        // P2
        RDB(b1, 0, 2);
        STG(T1, 1);
        FENCE();
        MM16(am, b1, 0, 2);
        __builtin_amdgcn_s_barrier();
        // P3
        RDA(am, 0, 4);
        STG(T1 + 1, 2);
        FENCE();
        MM16(am, b1, 4, 2);
        __builtin_amdgcn_s_barrier();
        // P4
        STG(T1 + 1, 3);
        if (deep) asm volatile("s_waitcnt vmcnt(4)" ::: "memory");
        else      asm volatile("s_waitcnt vmcnt(0)" ::: "memory");
        FENCE();
        MM16(am, b0, 4, 0);
        __builtin_amdgcn_s_barrier();
        // P5
        RDA(am, 1, 0); RDB(b0, 1, 0);
        STG(T1 + 1, 0);
        FENCE();
        MM16(am, b0, 0, 0);
        __builtin_amdgcn_s_barrier();
        // P6
        RDB(b1, 1, 2);
        STG(T1 + 1, 1);
        FENCE();
        MM16(am, b1, 0, 2);
        __builtin_amdgcn_s_barrier();
        // P7
        RDA(am, 1, 4);
        STG(T1 + 2, 2);
        FENCE();
        MM16(am, b1, 4, 2);
        __builtin_amdgcn_s_barrier();
        // P8
        STG(T1 + 2, 3);
        if (deep) asm volatile("s_waitcnt vmcnt(4)" ::: "memory");
        else      asm volatile("s_waitcnt vmcnt(0)" ::: "memory");
        FENCE();
        MM16(am, b0, 4, 0);
        __builtin_amdgcn_s_barrier();
    }

    // ---- epilogue: C/D layout col = lane&15, row = quad*4 + reg
    const int mb = by * 256 + wm;
    const int nb = bx * 256 + wn;

    if (EPI == EPI_KV) {
        if (!isV) {        // K-proj: row-major bf16 + bias
            u16* Cp = (u16*)C + (long)b * sC;
            #pragma unroll
            for (int i = 0; i < 8; ++i)
                #pragma unroll
                for (int jn = 0; jn < 4; ++jn) {
                    const int col  = nb + jn * 16 + l16;
                    const int row0 = mb + i * 16 + quad * 4;
                    const float bs = bias[col];
                    #pragma unroll
                    for (int r = 0; r < 4; ++r)
                        Cp[(long)(row0 + r) * ldc + col] = f2bf(acc[i][jn][r] + bs);
                }
        } else {           // V-proj: transposed store C2^T[col][row0..+3]
            u16* Cp = (u16*)C2 + (long)b * sC2;
            #pragma unroll
            for (int i = 0; i < 8; ++i)
                #pragma unroll
                for (int jn = 0; jn < 4; ++jn) {
                    const int col  = nb + jn * 16 + l16;
                    const int row0 = mb + i * 16 + quad * 4;
                    const float bs = bias2[col];
                    const floatx4 vv = acc[i][jn];
                    ushort4 pk;
                    pk.x = f2bf(vv[0] + bs); pk.y = f2bf(vv[1] + bs);
                    pk.z = f2bf(vv[2] + bs); pk.w = f2bf(vv[3] + bs);
                    *(ushort4*)(Cp + (long)col * ldc2 + row0) = pk;
                }
        }
    }
}

// ---------------------------------------------------------------------------
extern "C" void kernel_launch(void* const* d_in, const int* in_sizes, int n_in,
                              void* d_out, int out_size, void* d_ws, size_t ws_size,
                              hipStream_t stream)
{
    const float* Q  = (const float*)d_in[0];
    const float* K  = (const float*)d_in[1];
    const float* V  = (const float*)d_in[2];
    const float* Wk = (const float*)d_in[3];
    const float* bk = (const float*)d_in[4];
    const float* Wv = (const float*)d_in[5];
    const float* bv = (const float*)d_in[6];
    const float* Wo = (const float*)d_in[7];
    const float* bo = (const float*)d_in[8];
    float* out = (float*)d_out;

    // Workspace layout (max extent 94.4 MB + 16 KB):
    char* ws = (char*)d_ws;
    u16*   Kbf  = (u16*)(ws);
    u16*   Vbf  = (u16*)(ws + 22020096);
    u16*   Qbf  = (u16*)(ws + 44040192);
    u16*   Wkbf = (u16*)(ws + 52828160);
    u16*   Wvbf = (u16*)(ws + 55574528);
    u16*   Wobf = (u16*)(ws + 58320896);
    u16*   Kp   = (u16*)(ws + 60817408);
    u16*   VpT  = (u16*)(ws + 77594624);
    u16*   E    = (u16*)(ws);
    float* rsum = (float*)(ws + 94371840);
    u16*   Ctx  = Kp;

    const float inv_sqrt_d = 0.03125f;   // 1/sqrt(1024)

    // ---- one batched cast launch (also zeroes rsum)
    CastDesc cd;
    cd.src[0] = K;  cd.dst[0] = Kbf;
    cd.src[1] = V;  cd.dst[1] = Vbf;
    cd.src[2] = Q;  cd.dst[2] = Qbf;
    cd.src[3] = Wk; cd.dst[3] = Wkbf;
    cd.src[4] = Wv; cd.dst[4] = Wvbf;
    cd.src[5] = Wo; cd.dst[5] = Wobf;
    long acc = 0;
    const long sizes[6] = {(long)BB*LK*D2, (long)BB*LK*D2, (long)BB*LQ*D1,
                           (long)D1*D2, (long)D1*D2, (long)D1*D1};
    for (int i = 0; i < 6; ++i) { acc += sizes[i] / 4; cd.end[i] = acc; }
    cast6_kernel<<<dim3((unsigned)((acc + 255) / 256)), 256, 0, stream>>>(cd, acc, rsum);

    // ---- merged K/V projections: 8-phase 256x256, grid 32 x z=8 = 256 blocks
    mm256<EPI_KV><<<dim3((D1/256)*(LK/256), 1, 2*BB), 512, 0, stream>>>(
        Kbf, Wkbf, Kp, bk, D1/256, D2, D2, D2, D1,
        (long)LK*D2, 0, (long)LK*D1, 1.0f,
        Vbf, Wvbf, VpT, bv, LK, (long)D1*LK, nullptr);

    // ---- fused scores+exp: 2-phase 128x128, 512 blocks (R14 revert — the
    // mm256 version's 128-block grid left half the GPU idle)
    mm_bf16<128, 128, EPI_EXP><<<dim3((LK/128)*(LQ/128), 1, BB), 256, 0, stream>>>(
        Qbf, Kp, E, nullptr, LK/128, D1, D1, D1, LK,
        (long)LQ*D1, (long)LK*D1, (long)LQ*LK, inv_sqrt_d,
        nullptr, nullptr, nullptr, nullptr, 0, 0, rsum);

    // ---- context with fused normalization: Ctx = (E @ VpT^T) / rsum[row]
    mm_bf16<128, 64, EPI_ROWSCALE><<<dim3((D1/64)*(LQ/128), 1, BB), 256, 0, stream>>>(
        E, VpT, Ctx, nullptr, D1/64, LK, LK, LK, D1,
        (long)LQ*LK, (long)D1*LK, (long)LQ*D1, 1.0f,
        nullptr, nullptr, nullptr, nullptr, 0, 0, rsum);

    // ---- output: out = Ctx @ Wo^T + bo
    mm_bf16<128, 64, EPI_F32_BIAS><<<dim3((D1/64)*((BB*LQ)/128), 1, 1), 256, 0, stream>>>(
        Ctx, Wobf, out, bo, D1/64, D1, D1, D1, D1, 0, 0, 0, 1.0f,
        nullptr, nullptr, nullptr, nullptr, 0, 0, nullptr);
}